// Round 1
// 115.857 us; speedup vs baseline: 1.1224x; 1.1224x over previous
//
#include <hip/hip_runtime.h>
#include <hip/hip_bf16.h>

// B=8, T1=128, T2=256, C=256, H=8, hd=32, E=32, A1=16, NTYPE=3. fp32 in HBM.
// Round 9: merge fused_gemm + attn_mfma into one kernel (qkv_attn, 193 blocks).
// Each block (i,b,h) computes its own 32-col head slice of q/k/v into LDS
// (same MFMA fragment math / K-order as r8 -> bit-identical values), then
// runs attention out of LDS. Removes one kernel boundary and the 7.5 MB
// qb/kbb/vbT global round-trip. prep and proj2 unchanged from r8.
#define NC 256
#define HD 32

typedef __attribute__((ext_vector_type(8))) short short8;
typedef __attribute__((ext_vector_type(4))) short short4v;
typedef __attribute__((ext_vector_type(4))) float f32x4;

#define QSC (0.17677669529663687f * 1.4426950408889634f)  // 1/sqrt(32)*log2(e)

__device__ __forceinline__ unsigned short f2bf(float f) {
    union { float f; unsigned u; } v; v.f = f;
    unsigned r = v.u + 0x7fffu + ((v.u >> 16) & 1u);   // RNE
    return (unsigned short)(r >> 16);
}
__device__ __forceinline__ short8 cvt8(float4 a, float4 b) {
    short8 s;
    s[0] = (short)f2bf(a.x); s[1] = (short)f2bf(a.y);
    s[2] = (short)f2bf(a.z); s[3] = (short)f2bf(a.w);
    s[4] = (short)f2bf(b.x); s[5] = (short)f2bf(b.y);
    s[6] = (short)f2bf(b.z); s[7] = (short)f2bf(b.w);
    return s;
}

// ---------------------------------------------------------------------------
// prep (UNCHANGED from r8): activations + masks + weight transposes.
// ---------------------------------------------------------------------------
__global__ __launch_bounds__(256) void prep(
    const float* __restrict__ x1, const float* __restrict__ x2,
    const float* __restrict__ ax1, const float* __restrict__ ax2,
    const int* __restrict__ masks,
    const float* __restrict__ Wq, const float* __restrict__ Wk,
    const float* __restrict__ Wv, const float* __restrict__ Wp,
    short* __restrict__ x1b, short* __restrict__ A2, short* __restrict__ ax1p,
    unsigned int* __restrict__ mb,
    short* __restrict__ WqT, short* __restrict__ WkT, short* __restrict__ WvT,
    short* __restrict__ WpT)
{
    const int bx = blockIdx.x, tid = threadIdx.x;
    const short8 zero8 = {0, 0, 0, 0, 0, 0, 0, 0};

    if (bx < 64) {
        const size_t base = ((size_t)bx * 256 + tid) * 16;
        const float* p = x1 + base;
        float4 a = *(const float4*)p,       b = *(const float4*)(p + 4);
        float4 c = *(const float4*)(p + 8), d = *(const float4*)(p + 12);
        *(short8*)&x1b[base]     = cvt8(a, b);
        *(short8*)&x1b[base + 8] = cvt8(c, d);
    } else if (bx < 352) {
        const int g = (bx - 64) * 256 + tid;
        const int row = g / 36, c8 = g - row * 36;
        short8 s;
        if (c8 < 32) {
            const float* p = x2 + (size_t)row * 256 + c8 * 8;
            s = cvt8(*(const float4*)p, *(const float4*)(p + 4));
        } else if (c8 < 34) {
            const float* p = ax2 + (size_t)row * 16 + (c8 - 32) * 8;
            s = cvt8(*(const float4*)p, *(const float4*)(p + 4));
        } else {
            s = zero8;
        }
        *(short8*)&A2[(size_t)row * 288 + c8 * 8] = s;
    } else if (bx < 356) {
        const int row = (bx - 352) * 256 + tid;
        const float* p = ax1 + (size_t)row * 16;
        float4 a = *(const float4*)p,       b = *(const float4*)(p + 4);
        float4 c = *(const float4*)(p + 8), d = *(const float4*)(p + 12);
        short* o = ax1p + (size_t)row * 32;
        *(short8*)o        = cvt8(a, b);
        *(short8*)(o + 8)  = cvt8(c, d);
        *(short8*)(o + 16) = zero8;
        *(short8*)(o + 24) = zero8;
    } else if (bx < 548) {
        const int r0 = (bx - 356) * 16;
        const int wave = tid >> 6, lane = tid & 63;
        for (int rr = 0; rr < 16; ++rr) {
            const int row = r0 + rr;
            const int mk = masks[(size_t)row * 256 + tid];
            unsigned long long bal = __ballot(mk != 0);
            if (lane == 0) {
                mb[row * 8 + wave * 2 + 0] = (unsigned int)bal;
                mb[row * 8 + wave * 2 + 1] = (unsigned int)(bal >> 32);
            }
        }
    } else if (bx < 644) {
        const int idx = bx - 548, i = idx >> 5, k8 = idx & 31;
        const int n = tid;
        const float* W = Wq + (size_t)i * 256 * 256;
        short8 s;
#pragma unroll
        for (int j = 0; j < 8; ++j) s[j] = (short)f2bf(W[(size_t)(k8 * 8 + j) * 256 + n]);
        *(short8*)&WqT[(size_t)i * 256 * 256 + (size_t)n * 256 + k8 * 8] = s;
    } else if (bx < 860) {
        const int idx0 = bx - 644;
        const int kv = idx0 / 108, idx = idx0 % 108;
        const int i = idx / 36, k8 = idx % 36;
        const int n = tid;
        const float* W = (kv ? Wv : Wk) + (size_t)i * 288 * 256;
        short* O = (kv ? WvT : WkT) + (size_t)i * 256 * 288;
        short8 s;
#pragma unroll
        for (int j = 0; j < 8; ++j) {
            const int kp = k8 * 8 + j;
            const int src = (kp < 256) ? kp : (kp < 272 ? kp + 16 : -1);
            s[j] = (src >= 0) ? (short)f2bf(W[(size_t)src * 256 + n]) : (short)0;
        }
        *(short8*)&O[(size_t)n * 288 + k8 * 8] = s;
    } else {
        const int idx = bx - 860, i = idx >> 5, k8 = idx & 31;
        const int n = tid;
        const float* W = Wp + (size_t)i * 256 * 256;
        short8 s;
#pragma unroll
        for (int j = 0; j < 8; ++j) s[j] = (short)f2bf(W[(size_t)(k8 * 8 + j) * 256 + n]);
        *(short8*)&WpT[(size_t)i * 256 * 256 + (size_t)n * 256 + k8 * 8] = s;
    }
}

// ---------------------------------------------------------------------------
// qkv_attn: 192 blocks = (i,b,h). Each block computes q(128x32), k(256x32),
// v(256x32, transposed) for its head slice into LDS with the SAME fragment
// expressions as r8's fused_gemm (bit-identical values), then runs the r8
// attention math out of LDS. Block 192 computes WeffT (as r8's bx==480).
// ---------------------------------------------------------------------------
__global__ __launch_bounds__(256) void qkv_attn(
    const short* __restrict__ x1b, const short* __restrict__ A2,
    const short* __restrict__ WqT, const short* __restrict__ WkT,
    const short* __restrict__ WvT, const float* __restrict__ Wv,
    const short* __restrict__ WpT,
    const float* __restrict__ bq, const float* __restrict__ bk,
    const float* __restrict__ bv, const unsigned int* __restrict__ mb,
    short* __restrict__ yb, short* __restrict__ WeffT)
{
    const int tid = threadIdx.x;
    const int wave = tid >> 6, lane = tid & 63;
    const int qd = lane >> 4, ml = lane & 15;
    const int bx = blockIdx.x;

    if (bx == 192) {   // WeffT = (sum_i Wv_a1_i @ Wp_i)^T  (r8 code, verbatim)
        f32x4 wacc[4];
#pragma unroll
        for (int nt = 0; nt < 4; ++nt) wacc[nt] = {0.f, 0.f, 0.f, 0.f};
        for (int i = 0; i < 3; ++i) {
            const float* Wvp = Wv + (size_t)i * 288 * 256;
            const short* Wpt = WpT + (size_t)i * 256 * 256;
            for (int step = 0; step < 8; ++step) {
                const float* ap = Wvp + (size_t)(256 + ml) * 256 + step * 32 + qd * 8;
                short8 af = cvt8(*(const float4*)ap, *(const float4*)(ap + 4));
#pragma unroll
                for (int nt = 0; nt < 4; ++nt) {
                    const int n = (wave * 4 + nt) * 16 + ml;
                    short8 bf = *(const short8*)&Wpt[(size_t)n * 256 + step * 32 + qd * 8];
                    wacc[nt] = __builtin_amdgcn_mfma_f32_16x16x32_bf16(af, bf, wacc[nt], 0, 0, 0);
                }
            }
        }
#pragma unroll
        for (int nt = 0; nt < 4; ++nt) {
            const int n = (wave * 4 + nt) * 16 + ml;
#pragma unroll
            for (int r = 0; r < 4; ++r) {
                WeffT[n * 32 + qd * 4 + r] = (short)f2bf(wacc[nt][r]);
                WeffT[n * 32 + 16 + qd * 4 + r] = 0;
            }
        }
        return;
    }

    const int i = bx >> 6, b = (bx >> 3) & 7, h = bx & 7;
    const size_t bb = (size_t)i * 8 + b;
    const int hc = h * 32;

    __shared__ short q_s[128][40];     // +8 pad: spreads row stride off bank 0
    __shared__ short k_s[256][40];
    __shared__ short vT_s[32][264];    // transposed v, +8 pad
    __shared__ short P_s[4][4096];     // per-wave P scratch (r8 layout)

    const short* Wq_i = WqT + (size_t)i * 256 * 256;
    const short* Wk_i = WkT + (size_t)i * 256 * 288;
    const short* Wv_i = WvT + (size_t)i * 256 * 288;

    // ---- Q: rows wave*32..+32, cols hc..hc+32, (x1b @ WqT + bq) * QSC ----
    {
        f32x4 acc[2][2];
#pragma unroll
        for (int mt = 0; mt < 2; ++mt)
#pragma unroll
            for (int nt = 0; nt < 2; ++nt) acc[mt][nt] = {0.f, 0.f, 0.f, 0.f};
        for (int step = 0; step < 8; ++step) {
            short8 af[2], bf[2];
#pragma unroll
            for (int mt = 0; mt < 2; ++mt)
                af[mt] = *(const short8*)&x1b[(size_t)(b * 128 + wave * 32 + mt * 16 + ml) * 256 + step * 32 + qd * 8];
#pragma unroll
            for (int nt = 0; nt < 2; ++nt)
                bf[nt] = *(const short8*)&Wq_i[(size_t)(hc + nt * 16 + ml) * 256 + step * 32 + qd * 8];
#pragma unroll
            for (int mt = 0; mt < 2; ++mt)
#pragma unroll
                for (int nt = 0; nt < 2; ++nt)
                    acc[mt][nt] = __builtin_amdgcn_mfma_f32_16x16x32_bf16(af[mt], bf[nt], acc[mt][nt], 0, 0, 0);
        }
#pragma unroll
        for (int nt = 0; nt < 2; ++nt) {
            const float bsv = bq[i * 256 + hc + nt * 16 + ml];
#pragma unroll
            for (int mt = 0; mt < 2; ++mt) {
                const int r0 = wave * 32 + mt * 16 + qd * 4;
#pragma unroll
                for (int r = 0; r < 4; ++r)
                    q_s[r0 + r][nt * 16 + ml] = (short)f2bf((acc[mt][nt][r] + bsv) * QSC);
            }
        }
    }

    // ---- K: s-rows wave*64..+64, cols hc..+32, A2 @ WkT + bk ----
    {
        f32x4 acc[4][2];
#pragma unroll
        for (int mt = 0; mt < 4; ++mt)
#pragma unroll
            for (int nt = 0; nt < 2; ++nt) acc[mt][nt] = {0.f, 0.f, 0.f, 0.f};
        for (int step = 0; step < 9; ++step) {
            short8 af[4], bf[2];
#pragma unroll
            for (int mt = 0; mt < 4; ++mt)
                af[mt] = *(const short8*)&A2[(size_t)(b * 256 + wave * 64 + mt * 16 + ml) * 288 + step * 32 + qd * 8];
#pragma unroll
            for (int nt = 0; nt < 2; ++nt)
                bf[nt] = *(const short8*)&Wk_i[(size_t)(hc + nt * 16 + ml) * 288 + step * 32 + qd * 8];
#pragma unroll
            for (int mt = 0; mt < 4; ++mt)
#pragma unroll
                for (int nt = 0; nt < 2; ++nt)
                    acc[mt][nt] = __builtin_amdgcn_mfma_f32_16x16x32_bf16(af[mt], bf[nt], acc[mt][nt], 0, 0, 0);
        }
#pragma unroll
        for (int nt = 0; nt < 2; ++nt) {
            const float bsv = bk[i * 256 + hc + nt * 16 + ml];
#pragma unroll
            for (int mt = 0; mt < 4; ++mt) {
                const int s0 = wave * 64 + mt * 16 + qd * 4;
#pragma unroll
                for (int r = 0; r < 4; ++r)
                    k_s[s0 + r][nt * 16 + ml] = (short)f2bf(acc[mt][nt][r] + bsv);
            }
        }
    }

    // ---- V: s-rows wave*64..+64, cols hc..+32, transposed store ----
    {
        f32x4 acc[4][2];
#pragma unroll
        for (int mt = 0; mt < 4; ++mt)
#pragma unroll
            for (int nt = 0; nt < 2; ++nt) acc[mt][nt] = {0.f, 0.f, 0.f, 0.f};
        for (int step = 0; step < 9; ++step) {
            short8 af[4], bf[2];
#pragma unroll
            for (int mt = 0; mt < 4; ++mt)
                af[mt] = *(const short8*)&A2[(size_t)(b * 256 + wave * 64 + mt * 16 + ml) * 288 + step * 32 + qd * 8];
#pragma unroll
            for (int nt = 0; nt < 2; ++nt)
                bf[nt] = *(const short8*)&Wv_i[(size_t)(hc + nt * 16 + ml) * 288 + step * 32 + qd * 8];
#pragma unroll
            for (int mt = 0; mt < 4; ++mt)
#pragma unroll
                for (int nt = 0; nt < 2; ++nt)
                    acc[mt][nt] = __builtin_amdgcn_mfma_f32_16x16x32_bf16(af[mt], bf[nt], acc[mt][nt], 0, 0, 0);
        }
#pragma unroll
        for (int nt = 0; nt < 2; ++nt) {
            const float bsv = bv[i * 256 + hc + nt * 16 + ml];
#pragma unroll
            for (int mt = 0; mt < 4; ++mt) {
                const int s0 = wave * 64 + mt * 16 + qd * 4;
                short4v s;
                s.x = (short)f2bf(acc[mt][nt][0] + bsv);
                s.y = (short)f2bf(acc[mt][nt][1] + bsv);
                s.z = (short)f2bf(acc[mt][nt][2] + bsv);
                s.w = (short)f2bf(acc[mt][nt][3] + bsv);
                *(short4v*)&vT_s[nt * 16 + ml][s0] = s;
            }
        }
    }
    __syncthreads();

    // ---- attention (r8 math, q/k/v now in LDS); wave owns t rows wave*32..+32
    short* Pw = &P_s[wave][0];
    for (int mt = 0; mt < 2; ++mt) {
        const int t0 = wave * 32 + mt * 16;
        short8 af = *(const short8*)&q_s[t0 + ml][qd * 8];

        f32x4 sacc[16];
#pragma unroll
        for (int nt = 0; nt < 16; ++nt) sacc[nt] = {0.f, 0.f, 0.f, 0.f};
#pragma unroll
        for (int nt = 0; nt < 16; ++nt) {
            short8 bf = *(const short8*)&k_s[nt * 16 + ml][qd * 8];
            sacc[nt] = __builtin_amdgcn_mfma_f32_16x16x32_bf16(af, bf, sacc[nt], 0, 0, 0);
        }

        const int tb = t0 + qd * 4;
        uint4 wlo[4], whi[4];
#pragma unroll
        for (int r = 0; r < 4; ++r) {
            const unsigned int* p = mb + (bb * 128 + tb + r) * 8;
            wlo[r] = *(const uint4*)p;
            whi[r] = *(const uint4*)(p + 4);
        }

        f32x4 rs = {0.f, 0.f, 0.f, 0.f};
#pragma unroll
        for (int nt = 0; nt < 16; ++nt) {
#pragma unroll
            for (int r = 0; r < 4; ++r) {
                unsigned int w;
                switch (nt >> 1) {
                    case 0: w = wlo[r].x; break; case 1: w = wlo[r].y; break;
                    case 2: w = wlo[r].z; break; case 3: w = wlo[r].w; break;
                    case 4: w = whi[r].x; break; case 5: w = whi[r].y; break;
                    case 6: w = whi[r].z; break; default: w = whi[r].w; break;
                }
                const bool mk = (w >> ((nt & 1) * 16 + ml)) & 1u;
                float e = mk ? __builtin_amdgcn_exp2f(sacc[nt][r]) : 0.f;
                sacc[nt][r] = e;
                rs[r] += e;
            }
        }
#pragma unroll
        for (int off = 1; off <= 8; off <<= 1) {
#pragma unroll
            for (int r = 0; r < 4; ++r) rs[r] += __shfl_xor(rs[r], off);
        }
        f32x4 pinv, pfill;
#pragma unroll
        for (int r = 0; r < 4; ++r) {
            const bool z = (rs[r] == 0.f);
            pinv[r]  = z ? 0.f : 1.f / rs[r];
            pfill[r] = z ? (1.f / 256.f) : 0.f;
        }

#pragma unroll
        for (int nt = 0; nt < 16; ++nt) {
            const int sgrp = 2 * nt + (ml >> 3);
            const int pos = ml & 7;
#pragma unroll
            for (int r = 0; r < 4; ++r) {
                const float p = sacc[nt][r] * pinv[r] + pfill[r];
                Pw[(sgrp * 16 + qd * 4 + r) * 8 + pos] = (short)f2bf(p);
            }
        }

        f32x4 oacc[2];
        oacc[0] = {0.f, 0.f, 0.f, 0.f};
        oacc[1] = {0.f, 0.f, 0.f, 0.f};
#pragma unroll
        for (int ks = 0; ks < 8; ++ks) {
            short8 pa = *(const short8*)&Pw[((ks * 4 + qd) * 16 + ml) * 8];
#pragma unroll
            for (int n2 = 0; n2 < 2; ++n2) {
                short8 vf = *(const short8*)&vT_s[n2 * 16 + ml][ks * 32 + qd * 8];
                oacc[n2] = __builtin_amdgcn_mfma_f32_16x16x32_bf16(pa, vf, oacc[n2], 0, 0, 0);
            }
        }

#pragma unroll
        for (int n2 = 0; n2 < 2; ++n2) {
            const int d = hc + n2 * 16 + ml;
#pragma unroll
            for (int r = 0; r < 4; ++r)
                yb[(size_t)(bb * 128 + tb + r) * 256 + d] = (short)f2bf(oacc[n2][r]);
        }
    }
}

// ---------------------------------------------------------------------------
// proj2 (UNCHANGED from r8): out = sum_i O_i @ Wp_i + ax1 @ Weff + sum_i bp_i
// ---------------------------------------------------------------------------
__global__ __launch_bounds__(256) void proj2(
    const short* __restrict__ yb, const short* __restrict__ WpT,
    const short* __restrict__ ax1p, const short* __restrict__ WeffT,
    const float* __restrict__ bp, float* __restrict__ out)
{
    const int bx = blockIdx.x;
    const int m0 = (bx >> 2) * 16, n0 = (bx & 3) * 64;
    const int tid = threadIdx.x;
    const int wave = tid >> 6, lane = tid & 63;
    const int qd = lane >> 4, ml = lane & 15;
    const int col = n0 + wave * 16 + ml;

    f32x4 acc = {0.f, 0.f, 0.f, 0.f};

    for (int i = 0; i < 3; ++i) {
        const short* A = yb + (size_t)i * 1024 * 256;
        const short* W = WpT + (size_t)i * 256 * 256;
#pragma unroll
        for (int step = 0; step < 8; ++step) {
            short8 af = *(const short8*)&A[(size_t)(m0 + ml) * 256 + step * 32 + qd * 8];
            short8 bf = *(const short8*)&W[(size_t)col * 256 + step * 32 + qd * 8];
            acc = __builtin_amdgcn_mfma_f32_16x16x32_bf16(af, bf, acc, 0, 0, 0);
        }
    }
    {   // vaux term: ax1p(1024x32) @ WeffT, single K-step
        short8 af = *(const short8*)&ax1p[(size_t)(m0 + ml) * 32 + qd * 8];
        short8 bf = *(const short8*)&WeffT[(size_t)col * 32 + qd * 8];
        acc = __builtin_amdgcn_mfma_f32_16x16x32_bf16(af, bf, acc, 0, 0, 0);
    }
    const float b3 = bp[col] + bp[256 + col] + bp[512 + col];
    const int row0 = m0 + qd * 4;
#pragma unroll
    for (int r = 0; r < 4; ++r)
        out[(size_t)(row0 + r) * 256 + col] = acc[r] + b3;
}

extern "C" void kernel_launch(void* const* d_in, const int* in_sizes, int n_in,
                              void* d_out, int out_size, void* d_ws, size_t ws_size,
                              hipStream_t stream)
{
    const float* x1  = (const float*)d_in[0];
    const float* x2  = (const float*)d_in[1];
    const float* ax1 = (const float*)d_in[2];
    const float* ax2 = (const float*)d_in[3];
    const int*   mk  = (const int*)d_in[4];
    const float* Wq  = (const float*)d_in[5];
    const float* bq  = (const float*)d_in[6];
    const float* Wk  = (const float*)d_in[7];
    const float* bk  = (const float*)d_in[8];
    const float* Wv  = (const float*)d_in[9];
    const float* bv  = (const float*)d_in[10];
    const float* Wp  = (const float*)d_in[11];
    const float* bp  = (const float*)d_in[12];

    char* w = (char*)d_ws;
    short* x1b   = (short*)(w + 0);              // 512 KB
    short* A2    = (short*)(w + 524288);         // 1.125 MB
    short* ax1p  = (short*)(w + 1703936);        // 64 KB
    short* WqT   = (short*)(w + 1769472);        // 384 KB
    short* WkT   = (short*)(w + 2162688);        // 432 KB
    short* WvT   = (short*)(w + 2605056);        // 432 KB
    short* WpT   = (short*)(w + 3047424);        // 384 KB
    unsigned int* mbits = (unsigned int*)(w + 3440640);   // 96 KB
    short* WeffT = (short*)(w + 3538944);        // 16 KB
    short* yb    = (short*)(w + 3555328);        // 1.5 MB

    prep<<<dim3(956), 256, 0, stream>>>(x1, x2, ax1, ax2, mk, Wq, Wk, Wv, Wp,
                                        x1b, A2, ax1p, mbits, WqT, WkT, WvT, WpT);
    qkv_attn<<<dim3(193), 256, 0, stream>>>(x1b, A2, WqT, WkT, WvT, Wv, WpT,
                                            bq, bk, bv, mbits, yb, WeffT);
    proj2<<<dim3(256), 256, 0, stream>>>(yb, WpT, ax1p, WeffT, bp, (float*)d_out);
}